// Round 5
// baseline (4536.651 us; speedup 1.0000x reference)
//
#include <hip/hip_runtime.h>

typedef unsigned short ushort_t;
typedef unsigned int uint_t;
typedef __attribute__((ext_vector_type(8))) short short8;   // 8 bf16
typedef __attribute__((ext_vector_type(4))) float f32x4;
typedef __attribute__((ext_vector_type(4))) unsigned int u32x4;

#define B_ 32
#define T_ 512
#define H_ 512
#define XT_ 16384   // bf16 elems per timestep slot: 32wg * 32b * 16ch (blocked)

// ---------- bf16 helpers ----------
__device__ __forceinline__ float bf2f(ushort_t u) {
  union { unsigned int i; float f; } v; v.i = ((unsigned int)u) << 16; return v.f;
}
__device__ __forceinline__ ushort_t f2bf(float f) {
  union { float fv; unsigned int i; } v; v.fv = f;
  unsigned int x = v.i;
  x += 0x7fffu + ((x >> 16) & 1u);   // RNE
  return (ushort_t)(x >> 16);
}
__device__ __forceinline__ uint_t umin_(uint_t a, uint_t b) { return a < b ? a : b; }

// fast gate activations
__device__ __forceinline__ float fsig(float a) {
  return __builtin_amdgcn_rcpf(1.f + __expf(-a));
}
__device__ __forceinline__ float ftanh(float a) {
  return 1.f - 2.f * __builtin_amdgcn_rcpf(1.f + __expf(2.f * a));
}

// ---------- coherent (LLC) accesses ----------
__device__ __forceinline__ void cload16(short8& d, const ushort_t* p) {
  asm volatile("global_load_dwordx4 %0, %1, off sc0 sc1" : "=v"(d) : "v"(p) : "memory");
}
__device__ __forceinline__ void cload16u(u32x4& d, const uint_t* p) {
  asm volatile("global_load_dwordx4 %0, %1, off sc0 sc1" : "=v"(d) : "v"(p) : "memory");
}
__device__ __forceinline__ void cstore16(const short8& v, ushort_t* p) {
  asm volatile("global_store_dwordx4 %1, %0, off sc0 sc1" :: "v"(v), "v"(p) : "memory");
}
__device__ __forceinline__ void cstore8(unsigned long long v, uint_t* p) {
  asm volatile("global_store_dwordx2 %1, %0, off sc0 sc1" :: "v"(v), "v"(p) : "memory");
}
__device__ __forceinline__ void cstore4(uint_t v, ushort_t* p) {
  asm volatile("global_store_dword %1, %0, off sc0 sc1" :: "v"(v), "v"(p) : "memory");
}
#define WAIT_VM0 asm volatile("s_waitcnt vmcnt(0)" ::: "memory")
#define WAIT_VM1 asm volatile("s_waitcnt vmcnt(1)" ::: "memory")
#define WAIT_VM3 asm volatile("s_waitcnt vmcnt(3)" ::: "memory")
__device__ __forceinline__ void vfence(short8& v) { asm volatile("" : "+v"(v)); }

// ---------- flag rows ----------
__device__ __forceinline__ void poll_row(const int* row, int nf) {
  const int lane = threadIdx.x & 63;
  if (nf > 64) {
    for (;;) {
      int a = __hip_atomic_load(row + lane,      __ATOMIC_RELAXED, __HIP_MEMORY_SCOPE_AGENT);
      int b = __hip_atomic_load(row + 64 + lane, __ATOMIC_RELAXED, __HIP_MEMORY_SCOPE_AGENT);
      if (__all(a != 0 && b != 0)) break;
      __builtin_amdgcn_s_sleep(1);
    }
  } else {
    for (;;) {
      int a = (lane < nf)
            ? __hip_atomic_load(row + lane, __ATOMIC_RELAXED, __HIP_MEMORY_SCOPE_AGENT) : 1;
      if (__all(a != 0)) break;
      __builtin_amdgcn_s_sleep(1);
    }
  }
  asm volatile("" ::: "memory");
}

// ---------- prep kernels ----------
__global__ void prep_w(const float* __restrict__ Wih, const float* __restrict__ Whh,
                       ushort_t* __restrict__ WihBf, ushort_t* __restrict__ WhhBf) {
  int i = blockIdx.x * 256 + threadIdx.x;
  WihBf[i] = f2bf(Wih[i]);
  WhhBf[i] = f2bf(Whh[i]);
}
// x [B][T][H] fp32 -> blocked [T][wg][b][ch16] bf16
__global__ void prep_x(const float* __restrict__ x, ushort_t* __restrict__ xA) {
  int i = blockIdx.x * 256 + threadIdx.x;
  int ch = i & 15;
  int b  = (i >> 4) & 31;
  int wg = (i >> 9) & 31;
  int t  = i >> 14;
  xA[i] = f2bf(x[((size_t)b * T_ + t) * H_ + wg * 16 + ch]);
}

// ---------- one GRU layer stage (32 WGs) --------------------------------
// h exchange: TAGGED u32 (bf16 | (s+1)<<16) in blocked [p][wg][b][ch16] ->
// producer needs NO drain before publishing; consumer verifies tags, retries.
// x handoff: blocked bf16 + DEFERRED flags (vmcnt(3) guarantees step<=s-1
// stores acked; publish flag[s-1]) -> drain off the critical path.
__device__ void gru_stage(
    const ushort_t* __restrict__ xin, ushort_t* __restrict__ xout,
    const ushort_t* __restrict__ Wih, const ushort_t* __restrict__ Whh,
    const float* __restrict__ bih, const float* __restrict__ bhh,
    uint_t* __restrict__ hT,             // [2][32][32][16] tagged u32
    int* __restrict__ xFl,               // [T][128] deferred x flags
    int* __restrict__ hFl,               // [T][128] immediate h flags (pre-poll)
    const int* __restrict__ prodFl,      // [T][prodN] (null for L0)
    int prodN, int wg,
    float (*Gbuf)[2][48][33])
{
  const int tid   = threadIdx.x;
  const int lane  = tid & 63;
  const int wave  = tid >> 6;          // 0,1 = x-GEMM; 2,3 = h-GEMM
  const int jb    = wg * 16;
  const int m16   = lane & 15;
  const int quad  = lane >> 4;
  const int bcol  = (wave & 1) * 16 + m16;

  // Weight A-fragments resident in registers (A[m=lane&15][k=quad*8+j])
  const ushort_t* Wsel = (wave < 2) ? Wih : Whh;
  short8 afrag[3][16];
#pragma unroll
  for (int g = 0; g < 3; ++g) {
    const ushort_t* wp = Wsel + (size_t)(g * H_ + jb + m16) * H_ + quad * 8;
#pragma unroll
    for (int kk = 0; kk < 16; ++kk)
      afrag[g][kk] = *(const short8*)(wp + kk * 32);
  }

  // gate-math mapping: coalesced stores. b0 = tid>>3, c-pair = tid&7
  const int b0 = tid >> 3;
  const int c8 = tid & 7;
  const int c0 = 2 * c8, c1 = c0 + 1;
  const float bxr0 = bih[0*H_ + jb + c0], bhr0 = bhh[0*H_ + jb + c0];
  const float bxz0 = bih[1*H_ + jb + c0], bhz0 = bhh[1*H_ + jb + c0];
  const float bxn0 = bih[2*H_ + jb + c0], bhn0 = bhh[2*H_ + jb + c0];
  const float bxr1 = bih[0*H_ + jb + c1], bhr1 = bhh[0*H_ + jb + c1];
  const float bxz1 = bih[1*H_ + jb + c1], bhz1 = bhh[1*H_ + jb + c1];
  const float bxn1 = bih[2*H_ + jb + c1], bhn1 = bhh[2*H_ + jb + c1];
  float hp0 = 0.f, hp1 = 0.f;

  // lane-base offsets for blocked B-fragment loads:
  // k = kk*32 + quad*8 + j  ->  wg' = kk*2 + (quad>>1), ch = (quad&1)*8 + j
  const int xoff = (quad >> 1) * 512 + bcol * 16 + (quad & 1) * 8;   // bf16 units
  const uint_t* hb = hT + (quad >> 1) * 512 + bcol * 16 + (quad & 1) * 8;

  for (int s = 0; s < T_; ++s) {
    const int p = s & 1;
    f32x4 acc0 = {0.f, 0.f, 0.f, 0.f};
    f32x4 acc1 = acc0, acc2 = acc0;

    if (wave < 2) {
      const ushort_t* src = xin + (size_t)s * XT_ + xoff;
      if (prodFl) {
        poll_row(prodFl + s * prodN, prodN);   // flag[s] => x[s] acked in LLC
        short8 bfr[16];
#pragma unroll
        for (int kk = 0; kk < 16; ++kk) cload16(bfr[kk], src + kk * 1024);
        WAIT_VM0;
#pragma unroll
        for (int kk = 0; kk < 16; ++kk) {
          vfence(bfr[kk]);
          acc0 = __builtin_amdgcn_mfma_f32_16x16x32_bf16(afrag[0][kk], bfr[kk], acc0, 0, 0, 0);
          acc1 = __builtin_amdgcn_mfma_f32_16x16x32_bf16(afrag[1][kk], bfr[kk], acc1, 0, 0, 0);
          acc2 = __builtin_amdgcn_mfma_f32_16x16x32_bf16(afrag[2][kk], bfr[kk], acc2, 0, 0, 0);
        }
      } else {
        // layer 0: input from a prior dispatch -> plain cached loads
#pragma unroll
        for (int kk = 0; kk < 16; ++kk) {
          short8 bf = *(const short8*)(src + kk * 1024);
          acc0 = __builtin_amdgcn_mfma_f32_16x16x32_bf16(afrag[0][kk], bf, acc0, 0, 0, 0);
          acc1 = __builtin_amdgcn_mfma_f32_16x16x32_bf16(afrag[1][kk], bf, acc1, 0, 0, 0);
          acc2 = __builtin_amdgcn_mfma_f32_16x16x32_bf16(afrag[2][kk], bf, acc2, 0, 0, 0);
        }
      }
    } else if (s > 0) {
      // h-GEMM: cheap flag pre-poll (no producer drain!), then tagged verify
      poll_row(hFl + (s - 1) * 128, 128);
      const uint_t* hsrc = hb + p * 16384;
      const uint_t tgt = ((uint_t)s) << 16;    // stored tag = s (by step s-1)
      u32x4 t[32];
      for (;;) {
#pragma unroll
        for (int i = 0; i < 32; ++i)
          cload16u(t[i], hsrc + (i >> 1) * 1024 + (i & 1) * 4);
        WAIT_VM0;
        uint_t m = 0xffffffffu;
#pragma unroll
        for (int i = 0; i < 32; ++i)
          m = umin_(m, umin_(umin_(t[i].x, t[i].y), umin_(t[i].z, t[i].w)));
        if (__all(m >= tgt)) break;
        __builtin_amdgcn_s_sleep(2);
      }
#pragma unroll
      for (int kk = 0; kk < 16; ++kk) {
        union { uint_t w[4]; short8 v; } u;
        u.w[0] = __builtin_amdgcn_perm(t[2*kk].y,   t[2*kk].x,   0x05040100u);
        u.w[1] = __builtin_amdgcn_perm(t[2*kk].w,   t[2*kk].z,   0x05040100u);
        u.w[2] = __builtin_amdgcn_perm(t[2*kk+1].y, t[2*kk+1].x, 0x05040100u);
        u.w[3] = __builtin_amdgcn_perm(t[2*kk+1].w, t[2*kk+1].z, 0x05040100u);
        acc0 = __builtin_amdgcn_mfma_f32_16x16x32_bf16(afrag[0][kk], u.v, acc0, 0, 0, 0);
        acc1 = __builtin_amdgcn_mfma_f32_16x16x32_bf16(afrag[1][kk], u.v, acc1, 0, 0, 0);
        acc2 = __builtin_amdgcn_mfma_f32_16x16x32_bf16(afrag[2][kk], u.v, acc2, 0, 0, 0);
      }
    }
    // (h-wave at s==0: acc stays 0 == Whh @ h0)

    // C/D layout: col = lane&15 (batch), row = quad*4 + reg
    float (*Gd)[33] = Gbuf[p][(wave < 2) ? 0 : 1];
#pragma unroll
    for (int r = 0; r < 4; ++r) {
      Gd[ 0 + quad * 4 + r][bcol] = acc0[r];
      Gd[16 + quad * 4 + r][bcol] = acc1[r];
      Gd[32 + quad * 4 + r][bcol] = acc2[r];
    }
    __syncthreads();   // single barrier per step (parity LDS buffers)

    float (*Gx)[33] = Gbuf[p][0];
    float (*Gh)[33] = Gbuf[p][1];
    {
      float rr = fsig(Gx[c0][b0] + bxr0 + Gh[c0][b0] + bhr0);
      float zz = fsig(Gx[16 + c0][b0] + bxz0 + Gh[16 + c0][b0] + bhz0);
      float nn = ftanh(Gx[32 + c0][b0] + bxn0 + rr * (Gh[32 + c0][b0] + bhn0));
      hp0 = (1.f - zz) * nn + zz * hp0;
    }
    {
      float rr = fsig(Gx[c1][b0] + bxr1 + Gh[c1][b0] + bhr1);
      float zz = fsig(Gx[16 + c1][b0] + bxz1 + Gh[16 + c1][b0] + bhz1);
      float nn = ftanh(Gx[32 + c1][b0] + bxn1 + rr * (Gh[32 + c1][b0] + bhn1));
      hp1 = (1.f - zz) * nn + zz * hp1;
    }
    // tagged h publish (contiguous 512B per wave, NO drain before visibility)
    const uint_t tagv = (uint_t)(s + 1);
    uint_t v0 = (uint_t)f2bf(hp0), v1 = (uint_t)f2bf(hp1);
    unsigned long long hw = (unsigned long long)(v0 | (tagv << 16))
                          | ((unsigned long long)(v1 | (tagv << 16)) << 32);
    cstore8(hw, hT + ((s + 1) & 1) * 16384 + wg * 512 + b0 * 16 + c0);
    // x out (blocked bf16, contiguous 256B per wave)
    cstore4(v0 | (v1 << 16), xout + (size_t)s * XT_ + wg * 512 + b0 * 16 + c0);
    // immediate (un-drained) h flag; tag verify catches flag-before-data
    if (lane == 0)
      __hip_atomic_store(hFl + s * 128 + wg * 4 + wave, 1,
                         __ATOMIC_RELAXED, __HIP_MEMORY_SCOPE_AGENT);
    // deferred x flag: this step's 3 stores may be in flight; older are acked
    WAIT_VM3;
    if (s > 0 && lane == 0)
      __hip_atomic_store(xFl + (s - 1) * 128 + wg * 4 + wave, 1,
                         __ATOMIC_RELAXED, __HIP_MEMORY_SCOPE_AGENT);
  }
  WAIT_VM0;
  if (lane == 0)
    __hip_atomic_store(xFl + (T_ - 1) * 128 + wg * 4 + wave, 1,
                       __ATOMIC_RELAXED, __HIP_MEMORY_SCOPE_AGENT);
}

// ---------- LN stage (8 WGs): mask + LayerNorm; deferred self flags ----------
__device__ void ln_stage(
    const ushort_t* __restrict__ xin,
    ushort_t* __restrict__ xout_bf,       // mid-stack LN (blocked bf16 out)
    float* __restrict__ out_f32,          // final LN (fp32 d_out)
    const float* __restrict__ gamma, const float* __restrict__ beta,
    const int* __restrict__ seq,
    int* __restrict__ selfFl,             // [T][32]
    const int* __restrict__ prodFl, int prodN, int wg)
{
  const int lane = threadIdx.x & 63;
  const int wv   = threadIdx.x >> 6;
  const int b    = wg * 4 + wv;
  const int len  = seq[b];
  // blocked: h = (lane>>1)*16 + (lane&1)*8 + j == lane*8 + j
  const int off  = (lane >> 1) * 512 + b * 16 + (lane & 1) * 8;
  const int h0   = lane * 8;

  float g[8], be[8];
#pragma unroll
  for (int j = 0; j < 8; ++j) { g[j] = gamma[h0 + j]; be[j] = beta[h0 + j]; }

  for (int s = 0; s < T_; ++s) {
    poll_row(prodFl + s * prodN, prodN);
    short8 raw;
    cload16(raw, xin + (size_t)s * XT_ + off);
    WAIT_VM0;
    vfence(raw);
    const bool valid = s < len;
    float v[8];
#pragma unroll
    for (int j = 0; j < 8; ++j) v[j] = valid ? bf2f((ushort_t)raw[j]) : 0.f;

    float sum = 0.f, sq = 0.f;
#pragma unroll
    for (int j = 0; j < 8; ++j) { sum += v[j]; sq += v[j] * v[j]; }
#pragma unroll
    for (int o = 32; o > 0; o >>= 1) {
      sum += __shfl_xor(sum, o);
      sq  += __shfl_xor(sq, o);
    }
    float mu   = sum * (1.f / H_);
    float var  = sq * (1.f / H_) - mu * mu;
    float rstd = rsqrtf(var + 1e-5f);

    if (xout_bf) {
      short8 o8;
#pragma unroll
      for (int j = 0; j < 8; ++j)
        o8[j] = (short)f2bf((v[j] - mu) * rstd * g[j] + be[j]);
      cstore16(o8, xout_bf + (size_t)s * XT_ + off);
      WAIT_VM1;                              // previous step's store acked
      if (s > 0 && lane == 0)
        __hip_atomic_store(selfFl + (s - 1) * 32 + b, 1,
                           __ATOMIC_RELAXED, __HIP_MEMORY_SCOPE_AGENT);
    } else {
      float* dst = out_f32 + ((size_t)b * T_ + s) * H_ + h0;
#pragma unroll
      for (int j = 0; j < 8; ++j)
        dst[j] = (v[j] - mu) * rstd * g[j] + be[j];
    }
  }
  if (xout_bf) {
    WAIT_VM0;
    if (lane == 0)
      __hip_atomic_store(selfFl + (T_ - 1) * 32 + b, 1,
                         __ATOMIC_RELAXED, __HIP_MEMORY_SCOPE_AGENT);
  }
}

// ---------- fused pipelined kernel: 6 stages, 144 WGs -----------------------
// [0,32) L0: xA->xB  [32,64) L1: xB->xC  [64,72) LN0: xC->xA
// [72,104) L2: xA->xC  [104,136) L3: xC->xB  [136,144) LN1: xB->out
// Aliasing safe by flag causality (writer of slot s gated on prior reader).
__global__ __launch_bounds__(256, 1) void gru_mega(
    ushort_t* __restrict__ xA, ushort_t* __restrict__ xB, ushort_t* __restrict__ xC,
    const ushort_t* __restrict__ WihBf, const ushort_t* __restrict__ WhhBf,
    const float* __restrict__ bih, const float* __restrict__ bhh,
    const float* __restrict__ gamma, const float* __restrict__ beta,
    const int* __restrict__ seq,
    uint_t* __restrict__ hTbase, int* __restrict__ xflbase,
    int* __restrict__ hflbase, int* __restrict__ lnfl,
    float* __restrict__ out)
{
  __shared__ float Gbuf[2][2][48][33];

  const int bid = blockIdx.x;
  const int FS = T_ * 128;              // ints per GRU flag array
  const int WM = 3 * H_ * H_;
  const int HTS = 2 * 32 * 32 * 16;     // u32 per layer's tagged h

  if (bid < 32) {
    gru_stage(xA, xB, WihBf, WhhBf, bih, bhh,
              hTbase, xflbase, hflbase, nullptr, 0, bid, Gbuf);
  } else if (bid < 64) {
    gru_stage(xB, xC, WihBf + WM, WhhBf + WM, bih + 1536, bhh + 1536,
              hTbase + HTS, xflbase + FS, hflbase + FS,
              xflbase, 128, bid - 32, Gbuf);
  } else if (bid < 72) {
    ln_stage(xC, xA, nullptr, gamma, beta, seq, lnfl,
             xflbase + FS, 128, bid - 64);
  } else if (bid < 104) {
    gru_stage(xA, xC, WihBf + 2 * WM, WhhBf + 2 * WM, bih + 2 * 1536, bhh + 2 * 1536,
              hTbase + 2 * HTS, xflbase + 2 * FS, hflbase + 2 * FS,
              lnfl, 32, bid - 72, Gbuf);
  } else if (bid < 136) {
    gru_stage(xC, xB, WihBf + 3 * WM, WhhBf + 3 * WM, bih + 3 * 1536, bhh + 3 * 1536,
              hTbase + 3 * HTS, xflbase + 3 * FS, hflbase + 3 * FS,
              xflbase + 2 * FS, 128, bid - 104, Gbuf);
  } else {
    ln_stage(xB, nullptr, out, gamma + H_, beta + H_, seq,
             nullptr, xflbase + 3 * FS, 128, bid - 136);
  }
}

// ---------- workspace layout (bytes) ----------
#define WIH_OFF 0u
#define WHH_OFF 6291456u
#define XA_OFF  12582912u
#define XB_OFF  29360128u
#define XC_OFF  46137344u
#define HT_OFF  62914560u             // 4 * 131072 = 524288
#define XFL_OFF 63438848u             // 4 * 262144 = 1048576
#define HFL_OFF 64487424u             // 4 * 262144 = 1048576
#define LNF_OFF 65536000u             // 65536
// memset range: HT_OFF .. 65601536 (2686976 bytes); total ws ~65.6 MB

extern "C" void kernel_launch(void* const* d_in, const int* in_sizes, int n_in,
                              void* d_out, int out_size, void* d_ws, size_t ws_size,
                              hipStream_t stream) {
  (void)in_sizes; (void)n_in; (void)out_size; (void)ws_size;
  const float* x     = (const float*)d_in[0];
  const float* Wih   = (const float*)d_in[1];
  const float* Whh   = (const float*)d_in[2];
  const float* bih   = (const float*)d_in[3];
  const float* bhh   = (const float*)d_in[4];
  const float* gamma = (const float*)d_in[5];
  const float* beta  = (const float*)d_in[6];
  const int*   seq   = (const int*)d_in[7];

  char* ws = (char*)d_ws;
  ushort_t* WihBf = (ushort_t*)(ws + WIH_OFF);
  ushort_t* WhhBf = (ushort_t*)(ws + WHH_OFF);
  ushort_t* xA    = (ushort_t*)(ws + XA_OFF);
  ushort_t* xB    = (ushort_t*)(ws + XB_OFF);
  ushort_t* xC    = (ushort_t*)(ws + XC_OFF);
  uint_t*   hT    = (uint_t*)(ws + HT_OFF);
  int*      xfl   = (int*)(ws + XFL_OFF);
  int*      hfl   = (int*)(ws + HFL_OFF);
  int*      lnf   = (int*)(ws + LNF_OFF);

  // zero tagged-h (tags must start < 1) + all flags; ws poisoned 0xAA otherwise
  hipMemsetAsync(ws + HT_OFF, 0, 2686976u, stream);

  prep_w<<<12288, 256, 0, stream>>>(Wih, Whh, WihBf, WhhBf);
  prep_x<<<32768, 256, 0, stream>>>(x, xA);

  gru_mega<<<144, 256, 0, stream>>>(xA, xB, xC, WihBf, WhhBf,
                                    bih, bhh, gamma, beta, seq,
                                    hT, xfl, hfl, lnf, (float*)d_out);
}